// Round 1
// baseline (1152.547 us; speedup 1.0000x reference)
//
#include <hip/hip_runtime.h>

#define NN 50000
#define EE 800000
#define FIN 256
#define FH 128
#define FC 64
#define LPA_ITERS 10

// edge_index may arrive as int64 (reference dtype) or int32 (harness cast).
// Detection: as int32 words, int64 little-endian layout has every odd word == 0
// (values < 50000). Random row indices can't all be zero.
__device__ __forceinline__ int edge_at(const int* __restrict__ ei, int is32, int which, int e) {
    int idx = which * EE + e;
    return is32 ? ei[idx] : ei[2 * idx];
}

__global__ void detect_k(const unsigned int* __restrict__ w, int* __restrict__ flag) {
    int any = 0;
    for (int i = 1 + 2 * (int)threadIdx.x; i < 2048; i += 2 * (int)blockDim.x)
        if (w[i] != 0u) any = 1;
    if (any) atomicOr(flag, 1);
}

__global__ __launch_bounds__(256) void accum_k(const int* __restrict__ ei,
                                               const int* __restrict__ flag,
                                               const float* __restrict__ ea,
                                               float* __restrict__ deg,
                                               int* __restrict__ cnt) {
    int e = blockIdx.x * 256 + threadIdx.x;
    if (e >= EE) return;
    int is32 = *flag;
    int r = edge_at(ei, is32, 0, e);
    atomicAdd(&deg[r], ea[e]);
    atomicAdd(&cnt[r], 1);
}

// deg -> deg_inv in place; per-row CSR start via atomic offset allocation.
__global__ __launch_bounds__(256) void offsets_k(float* __restrict__ deg,
                                                 const int* __restrict__ cnt,
                                                 int* __restrict__ start,
                                                 int* __restrict__ fill,
                                                 int* __restrict__ gc) {
    int i = blockIdx.x * 256 + threadIdx.x;
    if (i >= NN) return;
    float d = deg[i];
    deg[i] = d > 0.f ? 1.f / d : 0.f;
    int s = atomicAdd(gc, cnt[i]);
    start[i] = s;
    fill[i] = s;
}

__global__ __launch_bounds__(256) void scatter_k(const int* __restrict__ ei,
                                                 const int* __restrict__ flag,
                                                 const float* __restrict__ ea,
                                                 const float* __restrict__ deginv,
                                                 int* __restrict__ fill,
                                                 int* __restrict__ csr_col,
                                                 float* __restrict__ csr_val) {
    int e = blockIdx.x * 256 + threadIdx.x;
    if (e >= EE) return;
    int is32 = *flag;
    int r = edge_at(ei, is32, 0, e);
    int c = edge_at(ei, is32, 1, e);
    int p = atomicAdd(&fill[r], 1);
    csr_col[p] = c;
    csr_val[p] = ea[e] * deginv[r];
}

// Simple 64x64 LDS-tiled f32 GEMM (no fp32 MFMA on CDNA4). C = A[M,K] @ B[K,Nn].
// Requires K % 16 == 0, Nn % 64 == 0 (true here: K in {256,128}, Nn in {128,64}).
__global__ __launch_bounds__(256) void sgemm_k(const float* __restrict__ A,
                                               const float* __restrict__ B,
                                               float* __restrict__ C,
                                               int M, int Nn, int K) {
    __shared__ float As[64 * 17];
    __shared__ float Bs[16 * 64];
    int t = threadIdx.x;
    int bm = blockIdx.x * 64, bn = blockIdx.y * 64;
    int tx = t & 15, ty = t >> 4;
    int arow = t >> 2, akc = (t & 3) * 4;
    int brow = t >> 4, bnc = (t & 15) * 4;
    float acc[4][4] = {};
    for (int k0 = 0; k0 < K; k0 += 16) {
        float4 av = make_float4(0.f, 0.f, 0.f, 0.f);
        int g = bm + arow;
        if (g < M) av = *(const float4*)&A[(size_t)g * K + k0 + akc];
        As[arow * 17 + akc + 0] = av.x;
        As[arow * 17 + akc + 1] = av.y;
        As[arow * 17 + akc + 2] = av.z;
        As[arow * 17 + akc + 3] = av.w;
        float4 bv = *(const float4*)&B[(size_t)(k0 + brow) * Nn + bn + bnc];
        Bs[brow * 64 + bnc + 0] = bv.x;
        Bs[brow * 64 + bnc + 1] = bv.y;
        Bs[brow * 64 + bnc + 2] = bv.z;
        Bs[brow * 64 + bnc + 3] = bv.w;
        __syncthreads();
#pragma unroll
        for (int kk = 0; kk < 16; ++kk) {
            float a[4], b[4];
#pragma unroll
            for (int i = 0; i < 4; ++i) a[i] = As[(ty * 4 + i) * 17 + kk];
#pragma unroll
            for (int j = 0; j < 4; ++j) b[j] = Bs[kk * 64 + tx * 4 + j];
#pragma unroll
            for (int i = 0; i < 4; ++i)
#pragma unroll
                for (int j = 0; j < 4; ++j) acc[i][j] = fmaf(a[i], b[j], acc[i][j]);
        }
        __syncthreads();
    }
#pragma unroll
    for (int i = 0; i < 4; ++i) {
        int g = bm + ty * 4 + i;
        if (g < M) {
            float4 o = make_float4(acc[i][0], acc[i][1], acc[i][2], acc[i][3]);
            *(float4*)&C[(size_t)g * Nn + bn + tx * 4] = o;
        }
    }
}

// Row-per-wave SpMM, F=64: lane == feature. out[r,:] = sum val[k] * m[col[k],:]
__global__ __launch_bounds__(256) void spmm64_k(const int* __restrict__ start,
                                                const int* __restrict__ cnt,
                                                const int* __restrict__ cols,
                                                const float* __restrict__ vals,
                                                const float* __restrict__ m,
                                                float* __restrict__ out,
                                                const float* __restrict__ bias,
                                                int relu) {
    int r = blockIdx.x * 4 + (threadIdx.x >> 6);
    if (r >= NN) return;
    int lane = threadIdx.x & 63;
    int s = start[r], e = s + cnt[r];
    float acc = 0.f;
    for (int k = s; k < e; ++k) {
        int c = cols[k];
        acc = fmaf(vals[k], m[c * 64 + lane], acc);
    }
    if (bias) acc += bias[lane];
    if (relu) acc = fmaxf(acc, 0.f);
    out[r * 64 + lane] = acc;
}

// Row-per-wave SpMM, F=128: each lane owns a float2 of features.
__global__ __launch_bounds__(256) void spmm128_k(const int* __restrict__ start,
                                                 const int* __restrict__ cnt,
                                                 const int* __restrict__ cols,
                                                 const float* __restrict__ vals,
                                                 const float* __restrict__ m,
                                                 float* __restrict__ out,
                                                 const float* __restrict__ bias,
                                                 int relu) {
    int r = blockIdx.x * 4 + (threadIdx.x >> 6);
    if (r >= NN) return;
    int lane = threadIdx.x & 63;
    const float2* m2 = (const float2*)m;
    float2 acc = make_float2(0.f, 0.f);
    int s = start[r], e = s + cnt[r];
    for (int k = s; k < e; ++k) {
        int c = cols[k];
        float v = vals[k];
        float2 t = m2[c * 64 + lane];
        acc.x = fmaf(v, t.x, acc.x);
        acc.y = fmaf(v, t.y, acc.y);
    }
    if (bias) {
        float2 b = ((const float2*)bias)[lane];
        acc.x += b.x;
        acc.y += b.y;
    }
    if (relu) {
        acc.x = fmaxf(acc.x, 0.f);
        acc.y = fmaxf(acc.y, 0.f);
    }
    ((float2*)out)[r * 64 + lane] = acc;
}

extern "C" void kernel_launch(void* const* d_in, const int* in_sizes, int n_in,
                              void* d_out, int out_size, void* d_ws, size_t ws_size,
                              hipStream_t stream) {
    const float* x    = (const float*)d_in[0];
    const float* soft = (const float*)d_in[1];
    const int*   ei   = (const int*)d_in[2];
    const float* ea   = (const float*)d_in[3];
    const float* W1   = (const float*)d_in[4];
    const float* b1   = (const float*)d_in[5];
    const float* W2   = (const float*)d_in[6];
    const float* b2   = (const float*)d_in[7];
    float* out  = (float*)d_out;                 // [N, C]
    float* labB = out + (size_t)NN * FC;         // [N, C] second output

    char* ws = (char*)d_ws;
    size_t off = 0;
    auto alloc = [&](size_t b) { size_t o = off; off += (b + 255) & ~(size_t)255; return o; };
    size_t o_misc  = alloc(256);                      // [0]=layout flag, [1]=gcounter
    size_t o_deg   = alloc((size_t)NN * 4);
    size_t o_cnt   = alloc((size_t)NN * 4);
    size_t zero_end = off;
    size_t o_start = alloc((size_t)NN * 4);
    size_t o_fill  = alloc((size_t)NN * 4);
    size_t o_ccol  = alloc((size_t)EE * 4);
    size_t o_cval  = alloc((size_t)EE * 4);
    size_t o_t1    = alloc((size_t)NN * FH * 4);      // xW1, later reused for hW2
    size_t o_h     = alloc((size_t)NN * FH * 4);
    size_t o_labA  = alloc((size_t)NN * FC * 4);
    if (off > ws_size) return;  // insufficient scratch -> visible failure

    int*   misc  = (int*)(ws + o_misc);
    float* deg   = (float*)(ws + o_deg);
    int*   cnt   = (int*)(ws + o_cnt);
    int*   start = (int*)(ws + o_start);
    int*   fill  = (int*)(ws + o_fill);
    int*   ccol  = (int*)(ws + o_ccol);
    float* cval  = (float*)(ws + o_cval);
    float* t1    = (float*)(ws + o_t1);
    float* h     = (float*)(ws + o_h);
    float* labA  = (float*)(ws + o_labA);

    hipMemsetAsync(d_ws, 0, zero_end, stream);
    detect_k<<<1, 256, 0, stream>>>((const unsigned int*)ei, &misc[0]);
    accum_k<<<(EE + 255) / 256, 256, 0, stream>>>(ei, misc, ea, deg, cnt);
    offsets_k<<<(NN + 255) / 256, 256, 0, stream>>>(deg, cnt, start, fill, &misc[1]);
    scatter_k<<<(EE + 255) / 256, 256, 0, stream>>>(ei, misc, ea, deg, fill, ccol, cval);

    // h = relu(spmm(x @ W1) + b1)
    sgemm_k<<<dim3((NN + 63) / 64, FH / 64), 256, 0, stream>>>(x, W1, t1, NN, FH, FIN);
    spmm128_k<<<(NN + 3) / 4, 256, 0, stream>>>(start, cnt, ccol, cval, t1, h, b1, 1);

    // out = spmm(h @ W2) + b2
    sgemm_k<<<dim3((NN + 63) / 64, FC / 64), 256, 0, stream>>>(h, W2, t1, NN, FC, FH);
    spmm64_k<<<(NN + 3) / 4, 256, 0, stream>>>(start, cnt, ccol, cval, t1, out, b2, 0);

    // labels: 10 x spmm, ping-pong labA <-> labB; iter 10 (even) lands in labB = d_out half 2
    const float* src = soft;
    float* dst = labA;
    for (int it = 0; it < LPA_ITERS; ++it) {
        spmm64_k<<<(NN + 3) / 4, 256, 0, stream>>>(start, cnt, ccol, cval, src, dst, nullptr, 0);
        src = dst;
        dst = (dst == labA) ? labB : labA;
    }
}

// Round 2
// 591.826 us; speedup vs baseline: 1.9474x; 1.9474x over previous
//
#include <hip/hip_runtime.h>

#define NN 50000
#define EE 800000
#define FIN 256
#define FH 128
#define FC 64
#define LPA_ITERS 10

// edge_index may arrive as int64 (reference dtype) or int32 (harness cast).
// Detection: as int32 words, int64 little-endian layout has every odd word == 0
// (values < 50000). Random row indices can't all be zero.
__device__ __forceinline__ int edge_at(const int* __restrict__ ei, int is32, int which, int e) {
    int idx = which * EE + e;
    return is32 ? ei[idx] : ei[2 * idx];
}

__global__ void detect_k(const unsigned int* __restrict__ w, int* __restrict__ flag) {
    int any = 0;
    for (int i = 1 + 2 * (int)threadIdx.x; i < 2048; i += 2 * (int)blockDim.x)
        if (w[i] != 0u) any = 1;
    if (any) atomicOr(flag, 1);
}

__global__ __launch_bounds__(256) void accum_k(const int* __restrict__ ei,
                                               const int* __restrict__ flag,
                                               const float* __restrict__ ea,
                                               float* __restrict__ deg,
                                               int* __restrict__ cnt) {
    int e = blockIdx.x * 256 + threadIdx.x;
    if (e >= EE) return;
    int is32 = *flag;
    int r = edge_at(ei, is32, 0, e);
    atomicAdd(&deg[r], ea[e]);
    atomicAdd(&cnt[r], 1);
}

// deg -> deg_inv in place; per-row CSR start via atomic offset allocation.
__global__ __launch_bounds__(256) void offsets_k(float* __restrict__ deg,
                                                 const int* __restrict__ cnt,
                                                 int* __restrict__ start,
                                                 int* __restrict__ fill,
                                                 int* __restrict__ gc) {
    int i = blockIdx.x * 256 + threadIdx.x;
    if (i >= NN) return;
    float d = deg[i];
    deg[i] = d > 0.f ? 1.f / d : 0.f;
    int s = atomicAdd(gc, cnt[i]);
    start[i] = s;
    fill[i] = s;
}

// CSR entries packed as uint2 {col, val bits}: one 8B load per edge.
__global__ __launch_bounds__(256) void scatter_k(const int* __restrict__ ei,
                                                 const int* __restrict__ flag,
                                                 const float* __restrict__ ea,
                                                 const float* __restrict__ deginv,
                                                 int* __restrict__ fill,
                                                 uint2* __restrict__ csr) {
    int e = blockIdx.x * 256 + threadIdx.x;
    if (e >= EE) return;
    int is32 = *flag;
    int r = edge_at(ei, is32, 0, e);
    int c = edge_at(ei, is32, 1, e);
    int p = atomicAdd(&fill[r], 1);
    float v = ea[e] * deginv[r];
    csr[p] = make_uint2((unsigned)c, __float_as_uint(v));
}

// Simple 64x64 LDS-tiled f32 GEMM (no fp32 MFMA on CDNA4). C = A[M,K] @ B[K,Nn].
__global__ __launch_bounds__(256) void sgemm_k(const float* __restrict__ A,
                                               const float* __restrict__ B,
                                               float* __restrict__ C,
                                               int M, int Nn, int K) {
    __shared__ float As[64 * 17];
    __shared__ float Bs[16 * 64];
    int t = threadIdx.x;
    int bm = blockIdx.x * 64, bn = blockIdx.y * 64;
    int tx = t & 15, ty = t >> 4;
    int arow = t >> 2, akc = (t & 3) * 4;
    int brow = t >> 4, bnc = (t & 15) * 4;
    float acc[4][4] = {};
    for (int k0 = 0; k0 < K; k0 += 16) {
        float4 av = make_float4(0.f, 0.f, 0.f, 0.f);
        int g = bm + arow;
        if (g < M) av = *(const float4*)&A[(size_t)g * K + k0 + akc];
        As[arow * 17 + akc + 0] = av.x;
        As[arow * 17 + akc + 1] = av.y;
        As[arow * 17 + akc + 2] = av.z;
        As[arow * 17 + akc + 3] = av.w;
        float4 bv = *(const float4*)&B[(size_t)(k0 + brow) * Nn + bn + bnc];
        Bs[brow * 64 + bnc + 0] = bv.x;
        Bs[brow * 64 + bnc + 1] = bv.y;
        Bs[brow * 64 + bnc + 2] = bv.z;
        Bs[brow * 64 + bnc + 3] = bv.w;
        __syncthreads();
#pragma unroll
        for (int kk = 0; kk < 16; ++kk) {
            float a[4], b[4];
#pragma unroll
            for (int i = 0; i < 4; ++i) a[i] = As[(ty * 4 + i) * 17 + kk];
#pragma unroll
            for (int j = 0; j < 4; ++j) b[j] = Bs[kk * 64 + tx * 4 + j];
#pragma unroll
            for (int i = 0; i < 4; ++i)
#pragma unroll
                for (int j = 0; j < 4; ++j) acc[i][j] = fmaf(a[i], b[j], acc[i][j]);
        }
        __syncthreads();
    }
#pragma unroll
    for (int i = 0; i < 4; ++i) {
        int g = bm + ty * 4 + i;
        if (g < M) {
            float4 o = make_float4(acc[i][0], acc[i][1], acc[i][2], acc[i][3]);
            *(float4*)&C[(size_t)g * Nn + bn + tx * 4] = o;
        }
    }
}

// SpMM F=64: quarter-wave (16 lanes x float4) per row; 16 rows per 256-block.
// 4-deep unroll -> up to 16 outstanding 256B gathers per wave.
__global__ __launch_bounds__(256) void spmm64_k(const int* __restrict__ start,
                                                const int* __restrict__ cnt,
                                                const uint2* __restrict__ csr,
                                                const float* __restrict__ m,
                                                float* __restrict__ out,
                                                const float* __restrict__ bias,
                                                int relu) {
    int t = threadIdx.x;
    int r = blockIdx.x * 16 + (t >> 4);
    if (r >= NN) return;
    int fl = t & 15;
    const float4* m4 = (const float4*)m;
    float4 acc = make_float4(0.f, 0.f, 0.f, 0.f);
    int s = start[r], n = cnt[r];
    int k = 0;
    for (; k + 4 <= n; k += 4) {
        uint2 e0 = csr[s + k], e1 = csr[s + k + 1], e2 = csr[s + k + 2], e3 = csr[s + k + 3];
        float4 g0 = m4[(size_t)e0.x * 16 + fl];
        float4 g1 = m4[(size_t)e1.x * 16 + fl];
        float4 g2 = m4[(size_t)e2.x * 16 + fl];
        float4 g3 = m4[(size_t)e3.x * 16 + fl];
        float v0 = __uint_as_float(e0.y), v1 = __uint_as_float(e1.y);
        float v2 = __uint_as_float(e2.y), v3 = __uint_as_float(e3.y);
        acc.x = fmaf(v0, g0.x, acc.x); acc.y = fmaf(v0, g0.y, acc.y);
        acc.z = fmaf(v0, g0.z, acc.z); acc.w = fmaf(v0, g0.w, acc.w);
        acc.x = fmaf(v1, g1.x, acc.x); acc.y = fmaf(v1, g1.y, acc.y);
        acc.z = fmaf(v1, g1.z, acc.z); acc.w = fmaf(v1, g1.w, acc.w);
        acc.x = fmaf(v2, g2.x, acc.x); acc.y = fmaf(v2, g2.y, acc.y);
        acc.z = fmaf(v2, g2.z, acc.z); acc.w = fmaf(v2, g2.w, acc.w);
        acc.x = fmaf(v3, g3.x, acc.x); acc.y = fmaf(v3, g3.y, acc.y);
        acc.z = fmaf(v3, g3.z, acc.z); acc.w = fmaf(v3, g3.w, acc.w);
    }
    for (; k < n; ++k) {
        uint2 e = csr[s + k];
        float v = __uint_as_float(e.y);
        float4 g = m4[(size_t)e.x * 16 + fl];
        acc.x = fmaf(v, g.x, acc.x); acc.y = fmaf(v, g.y, acc.y);
        acc.z = fmaf(v, g.z, acc.z); acc.w = fmaf(v, g.w, acc.w);
    }
    if (bias) {
        float4 b = ((const float4*)bias)[fl];
        acc.x += b.x; acc.y += b.y; acc.z += b.z; acc.w += b.w;
    }
    if (relu) {
        acc.x = fmaxf(acc.x, 0.f); acc.y = fmaxf(acc.y, 0.f);
        acc.z = fmaxf(acc.z, 0.f); acc.w = fmaxf(acc.w, 0.f);
    }
    ((float4*)out)[(size_t)r * 16 + fl] = acc;
}

// SpMM F=128: half-wave (32 lanes x float4) per row; 8 rows per 256-block.
__global__ __launch_bounds__(256) void spmm128_k(const int* __restrict__ start,
                                                 const int* __restrict__ cnt,
                                                 const uint2* __restrict__ csr,
                                                 const float* __restrict__ m,
                                                 float* __restrict__ out,
                                                 const float* __restrict__ bias,
                                                 int relu) {
    int t = threadIdx.x;
    int r = blockIdx.x * 8 + (t >> 5);
    if (r >= NN) return;
    int fl = t & 31;
    const float4* m4 = (const float4*)m;
    float4 acc = make_float4(0.f, 0.f, 0.f, 0.f);
    int s = start[r], n = cnt[r];
    int k = 0;
    for (; k + 4 <= n; k += 4) {
        uint2 e0 = csr[s + k], e1 = csr[s + k + 1], e2 = csr[s + k + 2], e3 = csr[s + k + 3];
        float4 g0 = m4[(size_t)e0.x * 32 + fl];
        float4 g1 = m4[(size_t)e1.x * 32 + fl];
        float4 g2 = m4[(size_t)e2.x * 32 + fl];
        float4 g3 = m4[(size_t)e3.x * 32 + fl];
        float v0 = __uint_as_float(e0.y), v1 = __uint_as_float(e1.y);
        float v2 = __uint_as_float(e2.y), v3 = __uint_as_float(e3.y);
        acc.x = fmaf(v0, g0.x, acc.x); acc.y = fmaf(v0, g0.y, acc.y);
        acc.z = fmaf(v0, g0.z, acc.z); acc.w = fmaf(v0, g0.w, acc.w);
        acc.x = fmaf(v1, g1.x, acc.x); acc.y = fmaf(v1, g1.y, acc.y);
        acc.z = fmaf(v1, g1.z, acc.z); acc.w = fmaf(v1, g1.w, acc.w);
        acc.x = fmaf(v2, g2.x, acc.x); acc.y = fmaf(v2, g2.y, acc.y);
        acc.z = fmaf(v2, g2.z, acc.z); acc.w = fmaf(v2, g2.w, acc.w);
        acc.x = fmaf(v3, g3.x, acc.x); acc.y = fmaf(v3, g3.y, acc.y);
        acc.z = fmaf(v3, g3.z, acc.z); acc.w = fmaf(v3, g3.w, acc.w);
    }
    for (; k < n; ++k) {
        uint2 e = csr[s + k];
        float v = __uint_as_float(e.y);
        float4 g = m4[(size_t)e.x * 32 + fl];
        acc.x = fmaf(v, g.x, acc.x); acc.y = fmaf(v, g.y, acc.y);
        acc.z = fmaf(v, g.z, acc.z); acc.w = fmaf(v, g.w, acc.w);
    }
    if (bias) {
        float4 b = ((const float4*)bias)[fl];
        acc.x += b.x; acc.y += b.y; acc.z += b.z; acc.w += b.w;
    }
    if (relu) {
        acc.x = fmaxf(acc.x, 0.f); acc.y = fmaxf(acc.y, 0.f);
        acc.z = fmaxf(acc.z, 0.f); acc.w = fmaxf(acc.w, 0.f);
    }
    ((float4*)out)[(size_t)r * 32 + fl] = acc;
}

extern "C" void kernel_launch(void* const* d_in, const int* in_sizes, int n_in,
                              void* d_out, int out_size, void* d_ws, size_t ws_size,
                              hipStream_t stream) {
    const float* x    = (const float*)d_in[0];
    const float* soft = (const float*)d_in[1];
    const int*   ei   = (const int*)d_in[2];
    const float* ea   = (const float*)d_in[3];
    const float* W1   = (const float*)d_in[4];
    const float* b1   = (const float*)d_in[5];
    const float* W2   = (const float*)d_in[6];
    const float* b2   = (const float*)d_in[7];
    float* out  = (float*)d_out;                 // [N, C]
    float* labB = out + (size_t)NN * FC;         // [N, C] second output

    char* ws = (char*)d_ws;
    size_t off = 0;
    auto alloc = [&](size_t b) { size_t o = off; off += (b + 255) & ~(size_t)255; return o; };
    size_t o_misc  = alloc(256);                      // [0]=layout flag, [1]=gcounter
    size_t o_deg   = alloc((size_t)NN * 4);
    size_t o_cnt   = alloc((size_t)NN * 4);
    size_t zero_end = off;
    size_t o_start = alloc((size_t)NN * 4);
    size_t o_fill  = alloc((size_t)NN * 4);
    size_t o_csr   = alloc((size_t)EE * 8);           // packed uint2 {col, val}
    size_t o_t1    = alloc((size_t)NN * FH * 4);      // xW1, later reused for hW2
    size_t o_h     = alloc((size_t)NN * FH * 4);
    size_t o_labA  = alloc((size_t)NN * FC * 4);
    if (off > ws_size) return;  // insufficient scratch -> visible failure

    int*   misc  = (int*)(ws + o_misc);
    float* deg   = (float*)(ws + o_deg);
    int*   cnt   = (int*)(ws + o_cnt);
    int*   start = (int*)(ws + o_start);
    int*   fill  = (int*)(ws + o_fill);
    uint2* csr   = (uint2*)(ws + o_csr);
    float* t1    = (float*)(ws + o_t1);
    float* h     = (float*)(ws + o_h);
    float* labA  = (float*)(ws + o_labA);

    hipMemsetAsync(d_ws, 0, zero_end, stream);
    detect_k<<<1, 256, 0, stream>>>((const unsigned int*)ei, &misc[0]);
    accum_k<<<(EE + 255) / 256, 256, 0, stream>>>(ei, misc, ea, deg, cnt);
    offsets_k<<<(NN + 255) / 256, 256, 0, stream>>>(deg, cnt, start, fill, &misc[1]);
    scatter_k<<<(EE + 255) / 256, 256, 0, stream>>>(ei, misc, ea, deg, fill, csr);

    // h = relu(spmm(x @ W1) + b1)
    sgemm_k<<<dim3((NN + 63) / 64, FH / 64), 256, 0, stream>>>(x, W1, t1, NN, FH, FIN);
    spmm128_k<<<(NN + 7) / 8, 256, 0, stream>>>(start, cnt, csr, t1, h, b1, 1);

    // out = spmm(h @ W2) + b2
    sgemm_k<<<dim3((NN + 63) / 64, FC / 64), 256, 0, stream>>>(h, W2, t1, NN, FC, FH);
    spmm64_k<<<(NN + 15) / 16, 256, 0, stream>>>(start, cnt, csr, t1, out, b2, 0);

    // labels: 10 x spmm, ping-pong labA <-> labB; iter 10 (even) lands in labB = d_out half 2
    const float* src = soft;
    float* dst = labA;
    for (int it = 0; it < LPA_ITERS; ++it) {
        spmm64_k<<<(NN + 15) / 16, 256, 0, stream>>>(start, cnt, csr, src, dst, nullptr, 0);
        src = dst;
        dst = (dst == labA) ? labB : labA;
    }
}